// Round 7
// baseline (155.964 us; speedup 1.0000x reference)
//
#include <hip/hip_runtime.h>
#include <hip/hip_bf16.h>
#include <hip/hip_fp16.h>

// EnhancedProxyNCALoss: B=4096, C=10000, D=128, SCALE=10, alpha=.25, gamma=2,
// k = int(9999*0.3) = 2999.
// R7: FUSED gemm+select. The 80 MB simk write + 80 MB re-read (L3 does not
//     allocate on write: R4 select FETCH = full re-fetch) is eliminated.
//     256 blocks x 512 thr; block owns 16 rows; LDS = 16 per-row packed
//     histograms (128 KB). Per col-tile: B-frags loaded straight from global
//     (B=2.56MB, per-XCD-L2-resident), 4 chained MFMA vs register A-frags,
//     keys -> ds_add_u32 packed hist (positive skipped by predicate).
//     Select finish is wave-local per row (no block barriers): suffix scan +
//     bin-mean denominator, numerically identical to R4/R6 fast path.

#define BATCH   4096
#define NCLASS  10000
#define EDIM    128
#define KSEL    2999
#define NBX     ((NCLASS + 127) / 128)   // 79 col tiles
#define MLOG    10.0f   // sim <= 10 always (cosine * SCALE) -> safe softmax max

typedef __attribute__((ext_vector_type(8))) short short8;
typedef __attribute__((ext_vector_type(4))) float floatx4;

__device__ __forceinline__ unsigned short f2bf(float f) {
    unsigned int u = __float_as_uint(f);
    unsigned int r = (u + 0x7FFFu + ((u >> 16) & 1u)) >> 16;   // RNE
    return (unsigned short)r;
}
// float -> half (RNE) -> monotonic 16-bit key (order-preserving)
__device__ __forceinline__ unsigned int f2key16(float x) {
    unsigned short hb = __half_as_ushort(__float2half(x));
    return (hb & 0x8000u) ? (unsigned int)(~hb & 0xFFFFu)
                          : (unsigned int)(hb | 0x8000u);
}
__device__ __forceinline__ float key16val(unsigned int k) {
    unsigned short hb = (k & 0x8000u) ? (unsigned short)(k ^ 0x8000u)
                                      : (unsigned short)(~k & 0xFFFFu);
    return __half2float(__ushort_as_half(hb));
}

// ---------------------------------------------------------------- prep ------
__global__ __launch_bounds__(256) void prep_kernel(
    const float* __restrict__ emb, const float* __restrict__ px,
    unsigned short* __restrict__ px_bf, unsigned short* __restrict__ emb_bf)
{
    const int tid  = threadIdx.x;
    const int lane = tid & 63;
    const int w    = tid >> 6;
    const int row  = blockIdx.x * 4 + w;   // grid = 3524 -> rows 0..14095

    const float* src;
    unsigned short* dst;
    float scale;
    if (row < NCLASS) {
        src = px + (size_t)row * EDIM;  dst = px_bf + (size_t)row * EDIM;  scale = 1.0f;
    } else {
        int r = row - NCLASS;
        src = emb + (size_t)r * EDIM;   dst = emb_bf + (size_t)r * EDIM;   scale = 10.0f;
    }
    float a = src[lane], b = src[lane + 64];
    float ss = a * a + b * b;
    #pragma unroll
    for (int off = 32; off; off >>= 1) ss += __shfl_xor(ss, off);
    float inv = scale / fmaxf(sqrtf(ss), 1e-12f);
    dst[lane]      = f2bf(a * inv);
    dst[lane + 64] = f2bf(b * inv);
}

// --------------------------------------------------------------- fused ------
__device__ __forceinline__ void load_bfrag(
    const unsigned short* __restrict__ px_bf, int ct, int wid, int lane,
    short8* dst)
{
    int col = ct * 128 + wid * 16 + (lane & 15);
    if (col > NCLASS - 1) col = NCLASS - 1;      // clamp; hist predicated off
    const unsigned short* bp = px_bf + (size_t)col * EDIM + ((lane >> 4) << 3);
    #pragma unroll
    for (int kk = 0; kk < 4; ++kk)
        dst[kk] = *(const short8*)(bp + kk * 32);
}

__global__ __launch_bounds__(512, 1) void fused_kernel(
    const unsigned short* __restrict__ emb_bf,
    const unsigned short* __restrict__ px_bf,
    const int* __restrict__ labels, const float* __restrict__ cw,
    float* __restrict__ partials)
{
    __shared__ __align__(16) unsigned int hist[16][2048];   // 128 KB packed
    __shared__ unsigned short s_poskey[16];

    const int tid  = threadIdx.x;
    const int lane = tid & 63;
    const int wid  = tid >> 6;              // 0..7 = 16-col subtile owner
    const int gr0  = blockIdx.x * 16;       // global row base (256 blocks)

    // zero hist: 512 threads x 64 words
    {
        uint4 z = make_uint4(0u, 0u, 0u, 0u);
        unsigned int* hp = &hist[0][0] + tid * 64;
        #pragma unroll
        for (int t = 0; t < 16; ++t) *(uint4*)(hp + t * 4) = z;
    }

    // A-frags: 16 rows resident in registers (lane&15 = row, lane>>4 = k-grp)
    short8 afr[4];
    {
        const unsigned short* ap =
            emb_bf + (size_t)(gr0 + (lane & 15)) * EDIM + ((lane >> 4) << 3);
        #pragma unroll
        for (int kk = 0; kk < 4; ++kk)
            afr[kk] = *(const short8*)(ap + kk * 32);
    }
    // labels for this lane's 4 output rows
    int lbl[4];
    #pragma unroll
    for (int r = 0; r < 4; ++r)
        lbl[r] = labels[gr0 + ((lane >> 4) << 2) + r];

    __syncthreads();                        // hist zeros visible

#define COMPUTE_CT(CT, BF)                                                    \
    do {                                                                      \
        floatx4 acc = (floatx4){0.f, 0.f, 0.f, 0.f};                          \
        _Pragma("unroll")                                                     \
        for (int kk = 0; kk < 4; ++kk)                                        \
            acc = __builtin_amdgcn_mfma_f32_16x16x32_bf16(                    \
                afr[kk], BF[kk], acc, 0, 0, 0);                               \
        int col = (CT) * 128 + wid * 16 + (lane & 15);                        \
        if (col < NCLASS) {                                                   \
            _Pragma("unroll")                                                 \
            for (int r = 0; r < 4; ++r) {                                     \
                int row = ((lane >> 4) << 2) + r;                             \
                unsigned int key = f2key16(acc[r]);                           \
                if (col == lbl[r])                                            \
                    s_poskey[row] = (unsigned short)key;                      \
                else                                                          \
                    atomicAdd(&hist[row][key >> 5],                           \
                              0x100000u | (key & 31u));                       \
            }                                                                 \
        }                                                                     \
    } while (0)

    // main loop over 79 col tiles, register-double-buffered B frags
    short8 bA[4], bB[4];
    load_bfrag(px_bf, 0, wid, lane, bA);
    for (int ct = 0; ct < NBX; ct += 2) {
        if (ct + 1 < NBX) load_bfrag(px_bf, ct + 1, wid, lane, bB);
        COMPUTE_CT(ct, bA);
        if (ct + 1 < NBX) {
            if (ct + 2 < NBX) load_bfrag(px_bf, ct + 2, wid, lane, bA);
            COMPUTE_CT(ct + 1, bB);
        }
    }
#undef COMPUTE_CT

    __syncthreads();                        // hists + poskeys complete

    // ---- select finish: wave wid owns rows 2*wid, 2*wid+1 (wave-local) ----
    #pragma unroll
    for (int rr = 0; rr < 2; ++rr) {
        const int row = wid * 2 + rr;
        // lane owns bins [lane*32, lane*32+32)
        unsigned int wd[32];
        #pragma unroll
        for (int t = 0; t < 8; ++t) {
            uint4 h = *(const uint4*)&hist[row][lane * 32 + t * 4];
            wd[t * 4 + 0] = h.x; wd[t * 4 + 1] = h.y;
            wd[t * 4 + 2] = h.z; wd[t * 4 + 3] = h.w;
        }
        unsigned int ltot = 0;
        #pragma unroll
        for (int i = 0; i < 32; ++i) ltot += wd[i] >> 20;
        // inclusive suffix over lanes (higher lanes = higher bins)
        unsigned int s = ltot;
        #pragma unroll
        for (int off = 1; off < 64; off <<= 1) {
            unsigned int o = __shfl_down(s, off);
            if (lane + off < 64) s += o;
        }
        const unsigned int above = s - ltot;   // keys in lanes strictly above
        // walk own bins high->low to find boundary bin
        unsigned int run = above, bbin = 0, fill = 0;
        bool found = false;
        #pragma unroll
        for (int i = 31; i >= 0; --i) {
            unsigned int c   = wd[i] >> 20;
            unsigned int cur = run + c;
            if (cur >= KSEL && run < KSEL) {
                found = true;
                bbin  = (unsigned int)(lane * 32 + i);
                fill  = KSEL - run;
            }
            run = cur;
        }
        unsigned long long m = __ballot(found);   // exactly one lane
        int src = __ffsll((long long)m) - 1;
        bbin = __shfl(bbin, src);
        fill = __shfl(fill, src);

        // denominator: per-bin mean exp (identical math to R4/R6 fast path)
        float sum = 0.f;
        #pragma unroll
        for (int i = 0; i < 32; ++i) {
            unsigned int bin = (unsigned int)(lane * 32 + i);
            unsigned int c   = wd[i] >> 20;
            if (bin >= bbin && c) {
                float rbar = (float)(wd[i] & 0xFFFFFu) / (float)c;
                unsigned int kb = bin << 5;
                float v0  = key16val(kb);
                float v32 = key16val(kb + 32u);
                float vm  = v0 + (v32 - v0) * (rbar * 0.03125f);
                float e   = __expf(vm - MLOG);
                sum += ((bin > bbin) ? (float)c : (float)fill) * e;
            }
        }
        #pragma unroll
        for (int off = 32; off; off >>= 1) sum += __shfl_xor(sum, off);

        if (lane == 0) {
            float sp = key16val((unsigned int)s_poskey[row]);
            float ep = __expf(sp - MLOG);
            float denom = sum + ep;
            float p  = ep / denom;
            float ce = -logf(p + 1e-8f);
            float focal = 0.25f * (1.0f - p) * (1.0f - p) * ce;
            partials[gr0 + row] = focal * cw[labels[gr0 + row]]
                                  * (1.0f / (float)BATCH);
        }
    }
}

// -------------------------------------------------------------- reduce ------
// Single block: sum 4096 partials -> out[0]. No atomics anywhere.
__global__ __launch_bounds__(256) void reduce_kernel(
    const float* __restrict__ partials, float* __restrict__ out)
{
    __shared__ float red[4];
    const int tid = threadIdx.x;
    float s = 0.f;
    #pragma unroll
    for (int t = 0; t < BATCH / 256; ++t)        // 16 loads/thread
        s += partials[tid + t * 256];
    #pragma unroll
    for (int off = 32; off; off >>= 1) s += __shfl_xor(s, off);
    if ((tid & 63) == 0) red[tid >> 6] = s;
    __syncthreads();
    if (tid == 0) out[0] = red[0] + red[1] + red[2] + red[3];
}

// ------------------------------------------------------------ launcher ------
extern "C" void kernel_launch(void* const* d_in, const int* in_sizes, int n_in,
                              void* d_out, int out_size, void* d_ws, size_t ws_size,
                              hipStream_t stream) {
    const float* emb    = (const float*)d_in[0];   // 4096 x 128
    const int*   labels = (const int*)d_in[1];     // 4096
    const float* cw     = (const float*)d_in[2];   // 10000
    const float* px     = (const float*)d_in[3];   // 10000 x 128
    float* out = (float*)d_out;
    char*  wsc = (char*)d_ws;

    unsigned short* px_bf  = (unsigned short*)wsc;               // 10000*128 bf16
    unsigned short* emb_bf = (unsigned short*)(wsc + 2560000);   // 4096*128 bf16
    float*          parts  = (float*)(wsc + 3608576);            // 4096 f32

    prep_kernel<<<3524, 256, 0, stream>>>(emb, px, px_bf, emb_bf);
    fused_kernel<<<BATCH / 16, 512, 0, stream>>>(emb_bf, px_bf, labels, cw, parts);
    reduce_kernel<<<1, 256, 0, stream>>>(parts, out);
}

// Round 8
// 147.880 us; speedup vs baseline: 1.0547x; 1.0547x over previous
//
#include <hip/hip_runtime.h>
#include <hip/hip_bf16.h>
#include <hip/hip_fp16.h>

// EnhancedProxyNCALoss: B=4096, C=10000, D=128, SCALE=10, alpha=.25, gamma=2,
// k = int(9999*0.3) = 2999.
// R8: fused gemm+select (R7 structure) with the latency fixed in-wave:
//   - dual interleaved MFMA chains (2 col-tiles per step, independent accs)
//   - 4-tile-deep named register prefetch (b0..b3) -> ~600cy load cover
//   - positive-only 1024-bin packed hist (negatives can never reach the
//     top-2999 boundary: ~5000 positives/row, 40 sigma margin) -> half the
//     DS atomics, 64 KB LDS, identical bin math (same 32-ULP bins).
// grid = 256 blocks x 512 thr, 1 block/CU; block owns 16 rows; B (2.56 MB)
// read straight from per-XCD L2 (R7 counters: FETCH 10.9 MB total).

#define BATCH   4096
#define NCLASS  10000
#define EDIM    128
#define KSEL    2999
#define NBX     ((NCLASS + 127) / 128)   // 79 col tiles (padded to 80)
#define MLOG    10.0f   // sim <= 10 always (cosine * SCALE) -> safe softmax max

typedef __attribute__((ext_vector_type(8))) short short8;
typedef __attribute__((ext_vector_type(4))) float floatx4;

__device__ __forceinline__ unsigned short f2bf(float f) {
    unsigned int u = __float_as_uint(f);
    unsigned int r = (u + 0x7FFFu + ((u >> 16) & 1u)) >> 16;   // RNE
    return (unsigned short)r;
}
// float -> half (RNE) -> monotonic 16-bit key (order-preserving)
__device__ __forceinline__ unsigned int f2key16(float x) {
    unsigned short hb = __half_as_ushort(__float2half(x));
    return (hb & 0x8000u) ? (unsigned int)(~hb & 0xFFFFu)
                          : (unsigned int)(hb | 0x8000u);
}
__device__ __forceinline__ float key16val(unsigned int k) {
    unsigned short hb = (k & 0x8000u) ? (unsigned short)(k ^ 0x8000u)
                                      : (unsigned short)(~k & 0xFFFFu);
    return __half2float(__ushort_as_half(hb));
}

// ---------------------------------------------------------------- prep ------
__global__ __launch_bounds__(256) void prep_kernel(
    const float* __restrict__ emb, const float* __restrict__ px,
    unsigned short* __restrict__ px_bf, unsigned short* __restrict__ emb_bf)
{
    const int tid  = threadIdx.x;
    const int lane = tid & 63;
    const int w    = tid >> 6;
    const int row  = blockIdx.x * 4 + w;   // grid = 3524 -> rows 0..14095

    const float* src;
    unsigned short* dst;
    float scale;
    if (row < NCLASS) {
        src = px + (size_t)row * EDIM;  dst = px_bf + (size_t)row * EDIM;  scale = 1.0f;
    } else {
        int r = row - NCLASS;
        src = emb + (size_t)r * EDIM;   dst = emb_bf + (size_t)r * EDIM;   scale = 10.0f;
    }
    float a = src[lane], b = src[lane + 64];
    float ss = a * a + b * b;
    #pragma unroll
    for (int off = 32; off; off >>= 1) ss += __shfl_xor(ss, off);
    float inv = scale / fmaxf(sqrtf(ss), 1e-12f);
    dst[lane]      = f2bf(a * inv);
    dst[lane + 64] = f2bf(b * inv);
}

// --------------------------------------------------------------- fused ------
__device__ __forceinline__ void load_bfrag(
    const unsigned short* __restrict__ px_bf, int ct, int wid, int lane,
    short8* dst)
{
    int col = ct * 128 + wid * 16 + (lane & 15);
    if (col > NCLASS - 1) col = NCLASS - 1;      // clamp; compute predicated
    const unsigned short* bp = px_bf + (size_t)col * EDIM + ((lane >> 4) << 3);
    #pragma unroll
    for (int kk = 0; kk < 4; ++kk)
        dst[kk] = *(const short8*)(bp + kk * 32);
}

__global__ __launch_bounds__(512, 1) void fused_kernel(
    const unsigned short* __restrict__ emb_bf,
    const unsigned short* __restrict__ px_bf,
    const int* __restrict__ labels, const float* __restrict__ cw,
    float* __restrict__ partials)
{
    __shared__ __align__(16) unsigned int hist[16][1024];   // 64 KB packed
    __shared__ unsigned short s_poskey[16];

    const int tid  = threadIdx.x;
    const int lane = tid & 63;
    const int wid  = tid >> 6;              // 0..7 = 16-col subtile owner
    const int gr0  = blockIdx.x * 16;       // global row base (256 blocks)

    // zero hist: 16384 words / 512 threads = 32 words each
    {
        uint4 z = make_uint4(0u, 0u, 0u, 0u);
        unsigned int* hp = &hist[0][0] + tid * 32;
        #pragma unroll
        for (int t = 0; t < 8; ++t) *(uint4*)(hp + t * 4) = z;
    }

    // A-frags: 16 rows resident in registers (lane&15 = row, lane>>4 = k-grp)
    short8 afr[4];
    {
        const unsigned short* ap =
            emb_bf + (size_t)(gr0 + (lane & 15)) * EDIM + ((lane >> 4) << 3);
        #pragma unroll
        for (int kk = 0; kk < 4; ++kk)
            afr[kk] = *(const short8*)(ap + kk * 32);
    }
    const int rbase = (lane >> 4) << 2;     // this lane's 4 output rows
    int lbl[4];
    #pragma unroll
    for (int r = 0; r < 4; ++r)
        lbl[r] = labels[gr0 + rbase + r];

    const int colbase = wid * 16 + (lane & 15);

    __syncthreads();                        // hist zeros visible

    // two independent interleaved MFMA chains + positive-only packed hist
#define COMPUTE2(CT, BX, BY)                                                  \
    do {                                                                      \
        floatx4 a0 = (floatx4){0.f, 0.f, 0.f, 0.f};                          \
        floatx4 a1 = (floatx4){0.f, 0.f, 0.f, 0.f};                          \
        a0 = __builtin_amdgcn_mfma_f32_16x16x32_bf16(afr[0], BX[0], a0, 0, 0, 0); \
        a1 = __builtin_amdgcn_mfma_f32_16x16x32_bf16(afr[0], BY[0], a1, 0, 0, 0); \
        a0 = __builtin_amdgcn_mfma_f32_16x16x32_bf16(afr[1], BX[1], a0, 0, 0, 0); \
        a1 = __builtin_amdgcn_mfma_f32_16x16x32_bf16(afr[1], BY[1], a1, 0, 0, 0); \
        a0 = __builtin_amdgcn_mfma_f32_16x16x32_bf16(afr[2], BX[2], a0, 0, 0, 0); \
        a1 = __builtin_amdgcn_mfma_f32_16x16x32_bf16(afr[2], BY[2], a1, 0, 0, 0); \
        a0 = __builtin_amdgcn_mfma_f32_16x16x32_bf16(afr[3], BX[3], a0, 0, 0, 0); \
        a1 = __builtin_amdgcn_mfma_f32_16x16x32_bf16(afr[3], BY[3], a1, 0, 0, 0); \
        const int cX = (CT) * 128 + colbase;                                  \
        const int cY = cX + 128;                                              \
        _Pragma("unroll")                                                     \
        for (int r = 0; r < 4; ++r) {                                         \
            const int row = rbase + r;                                        \
            unsigned int k0 = f2key16(a0[r]);                                 \
            if (cX < NCLASS) {                                                \
                if (cX == lbl[r]) s_poskey[row] = (unsigned short)k0;         \
                else if (k0 & 0x8000u)                                        \
                    atomicAdd(&hist[row][(k0 >> 5) & 1023u],                  \
                              0x100000u | (k0 & 31u));                        \
            }                                                                 \
            unsigned int k1 = f2key16(a1[r]);                                 \
            if (cY < NCLASS) {                                                \
                if (cY == lbl[r]) s_poskey[row] = (unsigned short)k1;         \
                else if (k1 & 0x8000u)                                        \
                    atomicAdd(&hist[row][(k1 >> 5) & 1023u],                  \
                              0x100000u | (k1 & 31u));                        \
            }                                                                 \
        }                                                                     \
    } while (0)

    // main loop: 80 padded tiles, 4-deep register prefetch, 2-tile compute
    short8 b0[4], b1[4], b2[4], b3[4];
    load_bfrag(px_bf, 0, wid, lane, b0);
    load_bfrag(px_bf, 1, wid, lane, b1);
    load_bfrag(px_bf, 2, wid, lane, b2);
    load_bfrag(px_bf, 3, wid, lane, b3);
    for (int ct = 0; ct < 80; ct += 4) {
        COMPUTE2(ct, b0, b1);
        load_bfrag(px_bf, ct + 4, wid, lane, b0);   // clamped past end
        load_bfrag(px_bf, ct + 5, wid, lane, b1);
        COMPUTE2(ct + 2, b2, b3);
        load_bfrag(px_bf, ct + 6, wid, lane, b2);
        load_bfrag(px_bf, ct + 7, wid, lane, b3);
    }
#undef COMPUTE2

    __syncthreads();                        // hists + poskeys complete

    // ---- select finish: wave wid owns rows 2*wid, 2*wid+1 (wave-local) ----
    #pragma unroll
    for (int rr = 0; rr < 2; ++rr) {
        const int row = wid * 2 + rr;
        // lane owns bins [lane*16, lane*16+16)  (bin+1024 = original key bin)
        unsigned int wd[16];
        #pragma unroll
        for (int t = 0; t < 4; ++t) {
            uint4 h = *(const uint4*)&hist[row][lane * 16 + t * 4];
            wd[t * 4 + 0] = h.x; wd[t * 4 + 1] = h.y;
            wd[t * 4 + 2] = h.z; wd[t * 4 + 3] = h.w;
        }
        unsigned int ltot = 0;
        #pragma unroll
        for (int i = 0; i < 16; ++i) ltot += wd[i] >> 20;
        // inclusive suffix over lanes (higher lanes = higher bins)
        unsigned int s = ltot;
        #pragma unroll
        for (int off = 1; off < 64; off <<= 1) {
            unsigned int o = __shfl_down(s, off);
            if (lane + off < 64) s += o;
        }
        const unsigned int above = s - ltot;   // keys in lanes strictly above
        // walk own bins high->low to find boundary bin
        unsigned int run = above, bbin = 0, fill = 0;
        bool found = false;
        #pragma unroll
        for (int i = 15; i >= 0; --i) {
            unsigned int c   = wd[i] >> 20;
            unsigned int cur = run + c;
            if (cur >= KSEL && run < KSEL) {
                found = true;
                bbin  = (unsigned int)(lane * 16 + i);
                fill  = KSEL - run;
            }
            run = cur;
        }
        unsigned long long m = __ballot(found);   // exactly one lane (or none
        if (m) {                                  // in the impossible case)
            int src = __ffsll((long long)m) - 1;
            bbin = __shfl(bbin, src);
            fill = __shfl(fill, src);
        } else { bbin = 0; fill = 0; }

        // denominator: per-bin mean exp (identical math to R4-R7)
        float sum = 0.f;
        #pragma unroll
        for (int i = 0; i < 16; ++i) {
            unsigned int bin = (unsigned int)(lane * 16 + i);
            unsigned int c   = wd[i] >> 20;
            if (bin >= bbin && c) {
                float rbar = (float)(wd[i] & 0xFFFFFu) / (float)c;
                unsigned int kb = (bin + 1024u) << 5;
                float v0  = key16val(kb);
                float v32 = key16val(kb + 32u);
                float vm  = v0 + (v32 - v0) * (rbar * 0.03125f);
                float e   = __expf(vm - MLOG);
                sum += ((bin > bbin) ? (float)c : (float)fill) * e;
            }
        }
        #pragma unroll
        for (int off = 32; off; off >>= 1) sum += __shfl_xor(sum, off);

        if (lane == 0) {
            float sp = key16val((unsigned int)s_poskey[row]);
            float ep = __expf(sp - MLOG);
            float denom = sum + ep;
            float p  = ep / denom;
            float ce = -logf(p + 1e-8f);
            float focal = 0.25f * (1.0f - p) * (1.0f - p) * ce;
            partials[gr0 + row] = focal * cw[labels[gr0 + row]]
                                  * (1.0f / (float)BATCH);
        }
    }
}

// -------------------------------------------------------------- reduce ------
// Single block: sum 4096 partials -> out[0]. No atomics anywhere.
__global__ __launch_bounds__(256) void reduce_kernel(
    const float* __restrict__ partials, float* __restrict__ out)
{
    __shared__ float red[4];
    const int tid = threadIdx.x;
    float s = 0.f;
    #pragma unroll
    for (int t = 0; t < BATCH / 256; ++t)        // 16 loads/thread
        s += partials[tid + t * 256];
    #pragma unroll
    for (int off = 32; off; off >>= 1) s += __shfl_xor(s, off);
    if ((tid & 63) == 0) red[tid >> 6] = s;
    __syncthreads();
    if (tid == 0) out[0] = red[0] + red[1] + red[2] + red[3];
}

// ------------------------------------------------------------ launcher ------
extern "C" void kernel_launch(void* const* d_in, const int* in_sizes, int n_in,
                              void* d_out, int out_size, void* d_ws, size_t ws_size,
                              hipStream_t stream) {
    const float* emb    = (const float*)d_in[0];   // 4096 x 128
    const int*   labels = (const int*)d_in[1];     // 4096
    const float* cw     = (const float*)d_in[2];   // 10000
    const float* px     = (const float*)d_in[3];   // 10000 x 128
    float* out = (float*)d_out;
    char*  wsc = (char*)d_ws;

    unsigned short* px_bf  = (unsigned short*)wsc;               // 10000*128 bf16
    unsigned short* emb_bf = (unsigned short*)(wsc + 2560000);   // 4096*128 bf16
    float*          parts  = (float*)(wsc + 3608576);            // 4096 f32

    prep_kernel<<<3524, 256, 0, stream>>>(emb, px, px_bf, emb_bf);
    fused_kernel<<<BATCH / 16, 512, 0, stream>>>(emb_bf, px_bf, labels, cw, parts);
    reduce_kernel<<<1, 256, 0, stream>>>(parts, out);
}

// Round 9
// 146.923 us; speedup vs baseline: 1.0615x; 1.0065x over previous
//
#include <hip/hip_runtime.h>
#include <hip/hip_bf16.h>
#include <hip/hip_fp16.h>

// EnhancedProxyNCALoss: B=4096, C=10000, D=128, SCALE=10, alpha=.25, gamma=2,
// k = int(9999*0.3) = 2999.
// R9: fused gemm+select, TLP doubled. R8 showed 1 block/CU x 8 waves = 25%
//     occupancy with 75% dead cycles (VALUBusy 21.7, MfmaUtil 4.8, HBM 1.6%).
//     Now 1024 threads / 16 waves per block: wave-group (wid>>3) takes
//     even/odd col-tiles, both groups share the per-row histograms (atomic
//     merge is free). 4 waves/SIMD. Everything else from R8 kept: dual MFMA
//     chains, 4-deep named register prefetch, positive-only 1024-bin packed
//     hist (one ds_add_u32 per positive key), wave-local finish (1 row/wave).

#define BATCH   4096
#define NCLASS  10000
#define EDIM    128
#define KSEL    2999
#define MLOG    10.0f   // sim <= 10 always (cosine * SCALE) -> safe softmax max

typedef __attribute__((ext_vector_type(8))) short short8;
typedef __attribute__((ext_vector_type(4))) float floatx4;

__device__ __forceinline__ unsigned short f2bf(float f) {
    unsigned int u = __float_as_uint(f);
    unsigned int r = (u + 0x7FFFu + ((u >> 16) & 1u)) >> 16;   // RNE
    return (unsigned short)r;
}
// float -> half (RNE) -> monotonic 16-bit key (order-preserving)
__device__ __forceinline__ unsigned int f2key16(float x) {
    unsigned short hb = __half_as_ushort(__float2half(x));
    return (hb & 0x8000u) ? (unsigned int)(~hb & 0xFFFFu)
                          : (unsigned int)(hb | 0x8000u);
}
__device__ __forceinline__ float key16val(unsigned int k) {
    unsigned short hb = (k & 0x8000u) ? (unsigned short)(k ^ 0x8000u)
                                      : (unsigned short)(~k & 0xFFFFu);
    return __half2float(__ushort_as_half(hb));
}

// ---------------------------------------------------------------- prep ------
__global__ __launch_bounds__(256) void prep_kernel(
    const float* __restrict__ emb, const float* __restrict__ px,
    unsigned short* __restrict__ px_bf, unsigned short* __restrict__ emb_bf)
{
    const int tid  = threadIdx.x;
    const int lane = tid & 63;
    const int w    = tid >> 6;
    const int row  = blockIdx.x * 4 + w;   // grid = 3524 -> rows 0..14095

    const float* src;
    unsigned short* dst;
    float scale;
    if (row < NCLASS) {
        src = px + (size_t)row * EDIM;  dst = px_bf + (size_t)row * EDIM;  scale = 1.0f;
    } else {
        int r = row - NCLASS;
        src = emb + (size_t)r * EDIM;   dst = emb_bf + (size_t)r * EDIM;   scale = 10.0f;
    }
    float a = src[lane], b = src[lane + 64];
    float ss = a * a + b * b;
    #pragma unroll
    for (int off = 32; off; off >>= 1) ss += __shfl_xor(ss, off);
    float inv = scale / fmaxf(sqrtf(ss), 1e-12f);
    dst[lane]      = f2bf(a * inv);
    dst[lane + 64] = f2bf(b * inv);
}

// --------------------------------------------------------------- fused ------
__device__ __forceinline__ void load_bfrag(
    const unsigned short* __restrict__ px_bf, int ct, int colbase,
    int lane, short8* dst)
{
    int col = ct * 128 + colbase;
    if (col > NCLASS - 1) col = NCLASS - 1;      // clamp; compute predicated
    const unsigned short* bp = px_bf + (size_t)col * EDIM + ((lane >> 4) << 3);
    #pragma unroll
    for (int kk = 0; kk < 4; ++kk)
        dst[kk] = *(const short8*)(bp + kk * 32);
}

__global__ __launch_bounds__(1024, 4) void fused_kernel(
    const unsigned short* __restrict__ emb_bf,
    const unsigned short* __restrict__ px_bf,
    const int* __restrict__ labels, const float* __restrict__ cw,
    float* __restrict__ partials)
{
    __shared__ __align__(16) unsigned int hist[16][1024];   // 64 KB packed
    __shared__ unsigned short s_poskey[16];

    const int tid  = threadIdx.x;
    const int lane = tid & 63;
    const int wid  = tid >> 6;              // 0..15
    const int g    = wid >> 3;              // tile-parity group: 0=even,1=odd
    const int gr0  = blockIdx.x * 16;       // global row base (256 blocks)

    // zero hist: 16384 words / 1024 threads = 16 words each
    {
        uint4 z = make_uint4(0u, 0u, 0u, 0u);
        unsigned int* hp = &hist[0][0] + tid * 16;
        #pragma unroll
        for (int t = 0; t < 4; ++t) *(uint4*)(hp + t * 4) = z;
    }

    // A-frags: 16 rows resident in registers (lane&15 = row, lane>>4 = k-grp)
    short8 afr[4];
    {
        const unsigned short* ap =
            emb_bf + (size_t)(gr0 + (lane & 15)) * EDIM + ((lane >> 4) << 3);
        #pragma unroll
        for (int kk = 0; kk < 4; ++kk)
            afr[kk] = *(const short8*)(ap + kk * 32);
    }
    const int rbase = (lane >> 4) << 2;     // this lane's 4 output rows
    int lbl[4];
    #pragma unroll
    for (int r = 0; r < 4; ++r)
        lbl[r] = labels[gr0 + rbase + r];

    const int colbase = (wid & 7) * 16 + (lane & 15);

    __syncthreads();                        // hist zeros visible

    // two independent interleaved MFMA chains + positive-only packed hist
#define COMPUTE2(CTA, CTB, BX, BY)                                            \
    do {                                                                      \
        floatx4 a0 = (floatx4){0.f, 0.f, 0.f, 0.f};                          \
        floatx4 a1 = (floatx4){0.f, 0.f, 0.f, 0.f};                          \
        a0 = __builtin_amdgcn_mfma_f32_16x16x32_bf16(afr[0], BX[0], a0, 0, 0, 0); \
        a1 = __builtin_amdgcn_mfma_f32_16x16x32_bf16(afr[0], BY[0], a1, 0, 0, 0); \
        a0 = __builtin_amdgcn_mfma_f32_16x16x32_bf16(afr[1], BX[1], a0, 0, 0, 0); \
        a1 = __builtin_amdgcn_mfma_f32_16x16x32_bf16(afr[1], BY[1], a1, 0, 0, 0); \
        a0 = __builtin_amdgcn_mfma_f32_16x16x32_bf16(afr[2], BX[2], a0, 0, 0, 0); \
        a1 = __builtin_amdgcn_mfma_f32_16x16x32_bf16(afr[2], BY[2], a1, 0, 0, 0); \
        a0 = __builtin_amdgcn_mfma_f32_16x16x32_bf16(afr[3], BX[3], a0, 0, 0, 0); \
        a1 = __builtin_amdgcn_mfma_f32_16x16x32_bf16(afr[3], BY[3], a1, 0, 0, 0); \
        const int cX = (CTA) * 128 + colbase;                                 \
        const int cY = (CTB) * 128 + colbase;                                 \
        _Pragma("unroll")                                                     \
        for (int r = 0; r < 4; ++r) {                                         \
            const int row = rbase + r;                                        \
            unsigned int k0 = f2key16(a0[r]);                                 \
            if (cX < NCLASS) {                                                \
                if (cX == lbl[r]) s_poskey[row] = (unsigned short)k0;         \
                else if (k0 & 0x8000u)                                        \
                    atomicAdd(&hist[row][(k0 >> 5) & 1023u],                  \
                              0x100000u | (k0 & 31u));                        \
            }                                                                 \
            unsigned int k1 = f2key16(a1[r]);                                 \
            if (cY < NCLASS) {                                                \
                if (cY == lbl[r]) s_poskey[row] = (unsigned short)k1;         \
                else if (k1 & 0x8000u)                                        \
                    atomicAdd(&hist[row][(k1 >> 5) & 1023u],                  \
                              0x100000u | (k1 & 31u));                        \
            }                                                                 \
        }                                                                     \
    } while (0)

    // wave-group g covers tiles {g, g+2, ..., g+78}; 4-deep named prefetch.
    // (tile 79 is padding: cols >= NCLASS predicated off, loads clamped)
    short8 b0[4], b1[4], b2[4], b3[4];
    load_bfrag(px_bf, g + 0, colbase, lane, b0);
    load_bfrag(px_bf, g + 2, colbase, lane, b1);
    load_bfrag(px_bf, g + 4, colbase, lane, b2);
    load_bfrag(px_bf, g + 6, colbase, lane, b3);
    for (int u = 0; u < 80; u += 8) {       // 10 iterations x 4 tiles
        COMPUTE2(g + u, g + u + 2, b0, b1);
        load_bfrag(px_bf, g + u + 8,  colbase, lane, b0);
        load_bfrag(px_bf, g + u + 10, colbase, lane, b1);
        COMPUTE2(g + u + 4, g + u + 6, b2, b3);
        load_bfrag(px_bf, g + u + 12, colbase, lane, b2);
        load_bfrag(px_bf, g + u + 14, colbase, lane, b3);
    }
#undef COMPUTE2

    __syncthreads();                        // hists + poskeys complete

    // ---- select finish: wave wid owns row wid (wave-local, no barriers) ----
    {
        const int row = wid;
        // lane owns bins [lane*16, lane*16+16)  (bin+1024 = original key bin)
        unsigned int wd[16];
        #pragma unroll
        for (int t = 0; t < 4; ++t) {
            uint4 h = *(const uint4*)&hist[row][lane * 16 + t * 4];
            wd[t * 4 + 0] = h.x; wd[t * 4 + 1] = h.y;
            wd[t * 4 + 2] = h.z; wd[t * 4 + 3] = h.w;
        }
        unsigned int ltot = 0;
        #pragma unroll
        for (int i = 0; i < 16; ++i) ltot += wd[i] >> 20;
        // inclusive suffix over lanes (higher lanes = higher bins)
        unsigned int s = ltot;
        #pragma unroll
        for (int off = 1; off < 64; off <<= 1) {
            unsigned int o = __shfl_down(s, off);
            if (lane + off < 64) s += o;
        }
        const unsigned int above = s - ltot;   // keys in lanes strictly above
        // walk own bins high->low to find boundary bin
        unsigned int run = above, bbin = 0, fill = 0;
        bool found = false;
        #pragma unroll
        for (int i = 15; i >= 0; --i) {
            unsigned int c   = wd[i] >> 20;
            unsigned int cur = run + c;
            if (cur >= KSEL && run < KSEL) {
                found = true;
                bbin  = (unsigned int)(lane * 16 + i);
                fill  = KSEL - run;
            }
            run = cur;
        }
        unsigned long long m = __ballot(found);   // exactly one lane (or none
        if (m) {                                  // in the impossible case)
            int src = __ffsll((long long)m) - 1;
            bbin = __shfl(bbin, src);
            fill = __shfl(fill, src);
        } else { bbin = 0; fill = 0; }

        // denominator: per-bin mean exp (identical math to R4-R8)
        float sum = 0.f;
        #pragma unroll
        for (int i = 0; i < 16; ++i) {
            unsigned int bin = (unsigned int)(lane * 16 + i);
            unsigned int c   = wd[i] >> 20;
            if (bin >= bbin && c) {
                float rbar = (float)(wd[i] & 0xFFFFFu) / (float)c;
                unsigned int kb = (bin + 1024u) << 5;
                float v0  = key16val(kb);
                float v32 = key16val(kb + 32u);
                float vm  = v0 + (v32 - v0) * (rbar * 0.03125f);
                float e   = __expf(vm - MLOG);
                sum += ((bin > bbin) ? (float)c : (float)fill) * e;
            }
        }
        #pragma unroll
        for (int off = 32; off; off >>= 1) sum += __shfl_xor(sum, off);

        if (lane == 0) {
            float sp = key16val((unsigned int)s_poskey[row]);
            float ep = __expf(sp - MLOG);
            float denom = sum + ep;
            float p  = ep / denom;
            float ce = -logf(p + 1e-8f);
            float focal = 0.25f * (1.0f - p) * (1.0f - p) * ce;
            partials[gr0 + row] = focal * cw[labels[gr0 + row]]
                                  * (1.0f / (float)BATCH);
        }
    }
}

// -------------------------------------------------------------- reduce ------
// Single block: sum 4096 partials -> out[0]. No atomics anywhere.
__global__ __launch_bounds__(256) void reduce_kernel(
    const float* __restrict__ partials, float* __restrict__ out)
{
    __shared__ float red[4];
    const int tid = threadIdx.x;
    float s = 0.f;
    #pragma unroll
    for (int t = 0; t < BATCH / 256; ++t)        // 16 loads/thread
        s += partials[tid + t * 256];
    #pragma unroll
    for (int off = 32; off; off >>= 1) s += __shfl_xor(s, off);
    if ((tid & 63) == 0) red[tid >> 6] = s;
    __syncthreads();
    if (tid == 0) out[0] = red[0] + red[1] + red[2] + red[3];
}

// ------------------------------------------------------------ launcher ------
extern "C" void kernel_launch(void* const* d_in, const int* in_sizes, int n_in,
                              void* d_out, int out_size, void* d_ws, size_t ws_size,
                              hipStream_t stream) {
    const float* emb    = (const float*)d_in[0];   // 4096 x 128
    const int*   labels = (const int*)d_in[1];     // 4096
    const float* cw     = (const float*)d_in[2];   // 10000
    const float* px     = (const float*)d_in[3];   // 10000 x 128
    float* out = (float*)d_out;
    char*  wsc = (char*)d_ws;

    unsigned short* px_bf  = (unsigned short*)wsc;               // 10000*128 bf16
    unsigned short* emb_bf = (unsigned short*)(wsc + 2560000);   // 4096*128 bf16
    float*          parts  = (float*)(wsc + 3608576);            // 4096 f32

    prep_kernel<<<3524, 256, 0, stream>>>(emb, px, px_bf, emb_bf);
    fused_kernel<<<BATCH / 16, 1024, 0, stream>>>(emb_bf, px_bf, labels, cw, parts);
    reduce_kernel<<<1, 256, 0, stream>>>(parts, out);
}

// Round 10
// 131.144 us; speedup vs baseline: 1.1893x; 1.1203x over previous
//
#include <hip/hip_runtime.h>
#include <hip/hip_bf16.h>
#include <hip/hip_fp16.h>

// EnhancedProxyNCALoss: B=4096, C=10000, D=128, SCALE=10, alpha=.25, gamma=2,
// k = int(9999*0.3) = 2999.
// Pipeline: prep (normalize+bf16, vectorized) ->
//           bf16 MFMA gemm (register-direct operands, LDS only for the
//           key16 transpose epilogue, XCD-swizzled grid) ->
//           per-row single-pass packed-histogram select (R6 verbatim) ->
//           1-block reduce.
// R10: fused path abandoned (R7-R9: 80us floor invariant to TLP/ILP/atomic
//      count; unexplained serializer). Back to verified R6 skeleton.
//      gemm: K=128 is ONE staged step -> LDS staging gives only 2x reuse;
//      drop it. Waves load A/B short8 frags straight from L2 per kk
//      (compile-time double-buffer), 16 MFMA/kk, 1 barrier (transpose only),
//      ~3 blocks/CU. prep: float2/ushort2 vectorized (same math).

#define BATCH   4096
#define NCLASS  10000
#define EDIM    128
#define KSEL    2999
#define LDK     136
#define MLOG    10.0f   // sim <= 10 always (cosine * SCALE) -> safe softmax max

typedef __attribute__((ext_vector_type(8))) short short8;
typedef __attribute__((ext_vector_type(4))) float floatx4;

__device__ __forceinline__ unsigned short f2bf(float f) {
    unsigned int u = __float_as_uint(f);
    unsigned int r = (u + 0x7FFFu + ((u >> 16) & 1u)) >> 16;   // RNE
    return (unsigned short)r;
}
// float -> half (RNE) -> monotonic 16-bit key (order-preserving)
__device__ __forceinline__ unsigned int f2key16(float x) {
    unsigned short hb = __half_as_ushort(__float2half(x));
    return (hb & 0x8000u) ? (unsigned int)(~hb & 0xFFFFu)
                          : (unsigned int)(hb | 0x8000u);
}
__device__ __forceinline__ float key16val(unsigned int k) {
    unsigned short hb = (k & 0x8000u) ? (unsigned short)(k ^ 0x8000u)
                                      : (unsigned short)(~k & 0xFFFFu);
    return __half2float(__ushort_as_half(hb));
}

// ---------------------------------------------------------------- prep ------
// lane handles elements 2*lane, 2*lane+1 (adjacent): float2 load, ushort2
// store -- coalesced both ways. Same normalization math as before.
__global__ __launch_bounds__(256) void prep_kernel(
    const float* __restrict__ emb, const float* __restrict__ px,
    unsigned short* __restrict__ px_bf, unsigned short* __restrict__ emb_bf)
{
    const int tid  = threadIdx.x;
    const int lane = tid & 63;
    const int w    = tid >> 6;
    const int row  = blockIdx.x * 4 + w;   // grid = 3524 -> rows 0..14095

    const float* src;
    unsigned short* dst;
    float scale;
    if (row < NCLASS) {
        src = px + (size_t)row * EDIM;  dst = px_bf + (size_t)row * EDIM;  scale = 1.0f;
    } else {
        int r = row - NCLASS;
        src = emb + (size_t)r * EDIM;   dst = emb_bf + (size_t)r * EDIM;   scale = 10.0f;
    }
    float2 v = *(const float2*)(src + 2 * lane);
    float ss = v.x * v.x + v.y * v.y;
    #pragma unroll
    for (int off = 32; off; off >>= 1) ss += __shfl_xor(ss, off);
    float inv = scale / fmaxf(sqrtf(ss), 1e-12f);
    ushort2 o;
    o.x = f2bf(v.x * inv);
    o.y = f2bf(v.y * inv);
    *(ushort2*)(dst + 2 * lane) = o;
}

// ---------------------------------------------------------------- gemm ------
// sim = emb10_hat . px_hat^T, 128x128 tile per block, 4 waves (64x64 each).
// Operands register-direct from L2 (no staging LDS, no staging barrier):
// per kk, each lane loads a[4],b[4] short8 frags; compile-time double-buffer
// pipelines kk+1 loads under kk's 16 MFMAs. Epilogue: key16 + LDS transpose
// (34.8 KB) + coalesced uint4 stores. XCD-swizzled 1-D grid (R6 mapping).
__global__ __launch_bounds__(256, 3) void gemm_kernel(
    const unsigned short* __restrict__ emb_bf,
    const unsigned short* __restrict__ px_bf,
    unsigned short* __restrict__ simk, int row0, int nby)
{
    __shared__ __align__(16) unsigned short T[128 * LDK];   // 34816 B

    const int NBX = (NCLASS + 127) / 128;   // 79 col tiles
    const int tid  = threadIdx.x;
    const int lane = tid & 63;
    const int w    = tid >> 6;

    // tile mapping: per-XCD row band, col-major walk inside the band
    int ct, rt;
    {
        int L = blockIdx.x;
        if ((nby & 7) == 0) {
            int rpx = nby >> 3;            // row tiles per XCD
            int xcd = L & 7;
            int s   = L >> 3;
            rt = xcd * rpx + (s % rpx);
            ct = s / rpx;
        } else {
            ct = L % NBX; rt = L / NBX;
        }
    }
    const int c0   = ct * 128;
    const int rg0  = row0 + rt * 128;

    const int wr = (w >> 1) * 64;
    const int wc = (w & 1) * 64;
    const int fm = lane & 15;
    const int fq = lane >> 4;

    // per-lane operand base pointers (row fixed per i/j, col walks with kk)
    const unsigned short* arow[4];
    const unsigned short* brow[4];
    #pragma unroll
    for (int i = 0; i < 4; ++i)
        arow[i] = emb_bf + (size_t)(rg0 + wr + i * 16 + fm) * EDIM + fq * 8;
    #pragma unroll
    for (int j = 0; j < 4; ++j) {
        int col = c0 + wc + j * 16 + fm;
        if (col > NCLASS - 1) col = NCLASS - 1;   // clamp; store predicated
        brow[j] = px_bf + (size_t)col * EDIM + fq * 8;
    }

    floatx4 acc[4][4];
    #pragma unroll
    for (int i = 0; i < 4; ++i)
        #pragma unroll
        for (int j = 0; j < 4; ++j)
            acc[i][j] = (floatx4){0.f, 0.f, 0.f, 0.f};

    // kk double-buffer (fully unrolled: all indices compile-time)
    short8 af[2][4], bf_[2][4];
    #pragma unroll
    for (int i = 0; i < 4; ++i) af[0][i]  = *(const short8*)(arow[i]);
    #pragma unroll
    for (int j = 0; j < 4; ++j) bf_[0][j] = *(const short8*)(brow[j]);

    #pragma unroll
    for (int kk = 0; kk < 4; ++kk) {
        const int cur = kk & 1, nxt = cur ^ 1;
        if (kk < 3) {
            const int kof = (kk + 1) * 32;
            #pragma unroll
            for (int i = 0; i < 4; ++i)
                af[nxt][i]  = *(const short8*)(arow[i] + kof);
            #pragma unroll
            for (int j = 0; j < 4; ++j)
                bf_[nxt][j] = *(const short8*)(brow[j] + kof);
        }
        #pragma unroll
        for (int i = 0; i < 4; ++i)
            #pragma unroll
            for (int j = 0; j < 4; ++j)
                acc[i][j] = __builtin_amdgcn_mfma_f32_16x16x32_bf16(
                    af[cur][i], bf_[cur][j], acc[i][j], 0, 0, 0);
    }

    // epilogue: key16 + transpose via LDS, coalesced uint4 stores
    // C/D layout: col = lane&15, row = (lane>>4)*4 + reg
    #pragma unroll
    for (int j = 0; j < 4; ++j) {
        int col = wc + j * 16 + fm;
        #pragma unroll
        for (int i = 0; i < 4; ++i) {
            int rbase = wr + i * 16 + fq * 4;
            #pragma unroll
            for (int r = 0; r < 4; ++r)
                T[(rbase + r) * LDK + col] = (unsigned short)f2key16(acc[i][j][r]);
        }
    }
    __syncthreads();

    const int rl0 = rt * 128;
    #pragma unroll
    for (int t = 0; t < 8; ++t) {
        int idx = t * 256 + tid;
        int rowl = idx >> 4;
        int g    = idx & 15;
        int col  = c0 + g * 8;
        if (col < NCLASS) {                // 10000 % 8 == 0 -> group all-valid
            uint4 v = *(const uint4*)(T + rowl * LDK + g * 8);
            *(uint4*)(simk + (size_t)(rl0 + rowl) * NCLASS + col) = v;
        }
    }
}

// -------------------------------------------------------------- select ------
// R6 verbatim. One block per batch row, single pass: packed histogram
// hist[bin] += (1<<20)|(key&31), suffix scan, per-bin-mean denominator,
// exact fallback for b<1024 (never taken on this data), plain store.
__global__ __launch_bounds__(256, 8) void select_kernel(
    const unsigned short* __restrict__ simk, const int* __restrict__ labels,
    const float* __restrict__ cw, float* __restrict__ partials, int row0)
{
    __shared__ __align__(16) unsigned int hist[2048];     // 8 KB (packed)
    __shared__ __align__(16) unsigned int psum[256];      // 1 KB
    __shared__ float fred[8];
    __shared__ float s_pos;
    __shared__ unsigned int s_b, s_fill, s_cntb;

    const int tid   = threadIdx.x;
    const int lane  = tid & 63;
    const int w     = tid >> 6;
    const int rl    = blockIdx.x;
    const int label = labels[row0 + rl];
    const unsigned short* srow = simk + (size_t)rl * NCLASS;

    // prefetch positive key early (consumed after hist barrier)
    unsigned short poskey = 0;
    if (tid == 0) poskey = srow[label];

    {
        uint4 z = make_uint4(0u, 0u, 0u, 0u);
        *(uint4*)&hist[tid * 8]     = z;
        *(uint4*)&hist[tid * 8 + 4] = z;
    }
    __syncthreads();            // hist zeros visible BEFORE loads issue ->
                                // atomics below overlap load arrival
    uint4 kv[5];
    kv[4] = make_uint4(0u, 0u, 0u, 0u);
    #pragma unroll
    for (int t = 0; t < 5; ++t) {
        int i = tid + t * 256;                       // 1250 groups total
        if (i < NCLASS / 8) kv[t] = *(const uint4*)(srow + i * 8);
    }

    // packed histogram: branchless, one u32 atomic per key
    #pragma unroll
    for (int t = 0; t < 5; ++t) {
        int i = tid + t * 256;
        if (i < NCLASS / 8) {
            unsigned int p[4] = {kv[t].x, kv[t].y, kv[t].z, kv[t].w};
            #pragma unroll
            for (int q = 0; q < 4; ++q) {
                unsigned int klo = p[q] & 0xFFFFu;
                unsigned int khi = p[q] >> 16;
                atomicAdd(&hist[klo >> 5], 0x100000u | (klo & 31u));
                atomicAdd(&hist[khi >> 5], 0x100000u | (khi & 31u));
            }
        }
    }
    __syncthreads();
    if (tid == 0) {
        s_pos = key16val(poskey);
        // exclude positive: dec count and its r contribution
        hist[poskey >> 5] -= 0x100000u | ((unsigned int)poskey & 31u);
    }
    __syncthreads();

    // ---- suffix scan over 2048 bins (counts); packed words kept live ----
    uint4 h0 = *(const uint4*)&hist[tid * 8];
    uint4 h1 = *(const uint4*)&hist[tid * 8 + 4];
    unsigned int wd[8] = {h0.x, h0.y, h0.z, h0.w, h1.x, h1.y, h1.z, h1.w};
    unsigned int sfx[8];
    sfx[7] = wd[7] >> 20;
    #pragma unroll
    for (int i = 6; i >= 0; --i) sfx[i] = sfx[i + 1] + (wd[i] >> 20);
    psum[tid] = sfx[0];
    __syncthreads();
    if (w == 0) {
        uint4 g = *(const uint4*)&psum[lane * 4];
        unsigned int gs = g.x + g.y + g.z + g.w;
        unsigned int s = gs;
        #pragma unroll
        for (int off = 1; off < 64; off <<= 1) {
            unsigned int o = __shfl_down(s, off);
            if (lane + off < 64) s += o;
        }
        unsigned int above = s - gs;       // partials in strictly-higher lanes
        unsigned int a3 = above;
        unsigned int a2 = a3 + g.w;
        unsigned int a1 = a2 + g.z;
        unsigned int a0 = a1 + g.y;
        psum[lane * 4 + 0] = a0; psum[lane * 4 + 1] = a1;
        psum[lane * 4 + 2] = a2; psum[lane * 4 + 3] = a3;
    }
    __syncthreads();
    {
        unsigned int add = psum[tid];      // keys in bins of threads > tid
        #pragma unroll
        for (int i = 0; i < 8; ++i) {
            unsigned int cur = sfx[i] + add;
            unsigned int nxt = ((i < 7) ? sfx[i + 1] : 0u) + add;
            if (cur >= KSEL && nxt < KSEL) {   // exactly one (tid,i) matches
                s_b    = (unsigned int)(tid * 8 + i);
                s_fill = KSEL - nxt;
                s_cntb = sfx[i] - ((i < 7) ? sfx[i + 1] : 0u);
            }
        }
    }
    __syncthreads();

    // ---- denominator ----
    const unsigned int b = s_b;
    float sum = 0.f, bsum = 0.f;           // bsum used by exact fallback only
    if (b >= 1024u) {
        // fast path: per-bin mean exp from packed words
        const float fillf = (float)s_fill;
        #pragma unroll
        for (int i = 0; i < 8; ++i) {
            unsigned int bin = (unsigned int)(tid * 8 + i);
            unsigned int c = wd[i] >> 20;
            if (bin >= b && c) {
                float rbar = (float)(wd[i] & 0xFFFFFu) / (float)c;
                unsigned int kb = bin << 5;
                float v0  = key16val(kb);
                float v32 = key16val(kb + 32u);
                float vm  = v0 + (v32 - v0) * (rbar * 0.03125f);
                float e = __expf(vm - MLOG);
                sum += ((bin > b) ? (float)c : fillf) * e;
            }
        }
    } else {
        // exact fallback: re-read keys (L3-hot), old two-class exp sum
        for (int i = tid; i < NCLASS / 8; i += 256) {
            uint4 pk = *(const uint4*)(srow + i * 8);
            unsigned int p[4] = {pk.x, pk.y, pk.z, pk.w};
            #pragma unroll
            for (int q = 0; q < 4; ++q) {
                unsigned int klo = p[q] & 0xFFFFu;
                unsigned int khi = p[q] >> 16;
                unsigned int blo = klo >> 5, bhi = khi >> 5;
                int idx = i * 8 + q * 2;
                if (blo >= b && idx != label) {
                    float e = __expf(key16val(klo) - MLOG);
                    if (blo > b) sum += e; else bsum += e;
                }
                if (bhi >= b && (idx + 1) != label) {
                    float e = __expf(key16val(khi) - MLOG);
                    if (bhi > b) sum += e; else bsum += e;
                }
            }
        }
    }
    #pragma unroll
    for (int off = 32; off; off >>= 1) {
        sum  += __shfl_xor(sum, off);
        bsum += __shfl_xor(bsum, off);
    }
    if (lane == 0) { fred[w] = sum; fred[4 + w] = bsum; }
    __syncthreads();

    if (tid == 0) {
        float S  = fred[0] + fred[1] + fred[2] + fred[3];
        float Bs = fred[4] + fred[5] + fred[6] + fred[7];   // 0 on fast path
        float ep = __expf(s_pos - MLOG);
        float denom = S + Bs * ((float)s_fill / (float)s_cntb) + ep;
        float p  = ep / denom;
        float ce = -logf(p + 1e-8f);
        float focal = 0.25f * (1.0f - p) * (1.0f - p) * ce;
        partials[row0 + rl] = focal * cw[label] * (1.0f / (float)BATCH);
    }
}

// -------------------------------------------------------------- reduce ------
// Single block: sum 4096 partials -> out[0]. No atomics anywhere.
__global__ __launch_bounds__(256) void reduce_kernel(
    const float* __restrict__ partials, float* __restrict__ out)
{
    __shared__ float red[4];
    const int tid = threadIdx.x;
    float s = 0.f;
    #pragma unroll
    for (int t = 0; t < BATCH / 256; ++t)        // 16 loads/thread
        s += partials[tid + t * 256];
    #pragma unroll
    for (int off = 32; off; off >>= 1) s += __shfl_xor(s, off);
    if ((tid & 63) == 0) red[tid >> 6] = s;
    __syncthreads();
    if (tid == 0) out[0] = red[0] + red[1] + red[2] + red[3];
}

// ------------------------------------------------------------ launcher ------
extern "C" void kernel_launch(void* const* d_in, const int* in_sizes, int n_in,
                              void* d_out, int out_size, void* d_ws, size_t ws_size,
                              hipStream_t stream) {
    const float* emb    = (const float*)d_in[0];   // 4096 x 128
    const int*   labels = (const int*)d_in[1];     // 4096
    const float* cw     = (const float*)d_in[2];   // 10000
    const float* px     = (const float*)d_in[3];   // 10000 x 128
    float* out = (float*)d_out;
    char*  wsc = (char*)d_ws;

    unsigned short* px_bf  = (unsigned short*)wsc;               // 10000*128 bf16
    unsigned short* emb_bf = (unsigned short*)(wsc + 2560000);   // 4096*128 bf16
    float*          parts  = (float*)(wsc + 3608576);            // 4096 f32
    unsigned short* simk   = (unsigned short*)(wsc + 3624960);   // chunk x 10000 key16

    size_t fixed = 3624960;
    size_t avail = (ws_size > fixed) ? (ws_size - fixed) : 0;
    long long cap = (long long)(avail / ((size_t)NCLASS * 2));
    int chunk = (int)((cap / 128) * 128);
    if (chunk > BATCH) chunk = BATCH;
    if (chunk < 128) chunk = 128;

    prep_kernel<<<3524, 256, 0, stream>>>(emb, px, px_bf, emb_bf);

    const int NBX = (NCLASS + 127) / 128;   // 79
    for (int r0 = 0; r0 < BATCH; r0 += chunk) {
        int rows = (BATCH - r0 < chunk) ? (BATCH - r0) : chunk;
        int nby  = rows / 128;
        gemm_kernel<<<NBX * nby, 256, 0, stream>>>(emb_bf, px_bf, simk, r0, nby);
        select_kernel<<<rows, 256, 0, stream>>>(simk, labels, cw, parts, r0);
    }
    reduce_kernel<<<1, 256, 0, stream>>>(parts, out);
}